// Round 6
// baseline (5761.523 us; speedup 1.0000x reference)
//
#include <hip/hip_runtime.h>
#include <hip/hip_fp16.h>

#define DS 256   // state_dim
#define DA 16    // act_dim
#define DH 30    // horizon
#define DHY 64   // hyper_dim
#define DB 64    // batch
#define DT 64    // seq len

// ---------------- setup kernels ----------------

__global__ __launch_bounds__(64) void k_hdist(const float* __restrict__ z,
                                              const float* __restrict__ tau,
                                              const float* __restrict__ tauw,
                                              float* __restrict__ h_dist) {
  const int bb = threadIdx.x;
  if (bb >= DB) return;
  float x = tau[0];
  for (int hy = 0; hy < DHY; ++hy) x = fmaf(z[bb * DHY + hy], tauw[hy], x);
  x = fminf(fmaxf(x, -8.f), 8.f);
  const float rate = __expf(x);
  const float lr = x;
  float lp[DH];
  float lg = 0.f;
  float mx = -1e30f;
  #pragma unroll
  for (int h = 0; h < DH; ++h) {
    const float ks = (float)(h + 1);
    lg += __logf(ks);
    lp[h] = ks * lr - rate - lg;
    mx = fmaxf(mx, lp[h]);
  }
  float sum = 0.f;
  #pragma unroll
  for (int h = 0; h < DH; ++h) { lp[h] = __expf(lp[h] - mx); sum += lp[h]; }
  const float inv = 1.f / sum;
  #pragma unroll
  for (int h = 0; h < DH; ++h) h_dist[bb * DH + h] = lp[h] * inv;
}

__global__ __launch_bounds__(256) void k_zero(float* __restrict__ out_pi,
                                              unsigned int* __restrict__ cnt) {
  const int i = blockIdx.x * 256 + threadIdx.x;
  out_pi[i] = 0.f;
  if (i < DB) cnt[i] = 0u;
}

// value fp32 -> fp16 (n4 = DH*DB*DA*DS/4)
__global__ __launch_bounds__(256) void k_vconv(const float* __restrict__ v,
                                               __half* __restrict__ v16, int n4) {
  const int stride = gridDim.x * 256;
  for (int i = blockIdx.x * 256 + threadIdx.x; i < n4; i += stride) {
    const float4 f = reinterpret_cast<const float4*>(v)[i];
    reinterpret_cast<__half2*>(v16)[2 * i]     = __floats2half2_rn(f.x, f.y);
    reinterpret_cast<__half2*>(v16)[2 * i + 1] = __floats2half2_rn(f.z, f.w);
  }
}

// transition[b,ki,j] = softmax_j(w[ki,j] + sum_hy z[b,hy]*wofs[(ki*S+j),hy]), fp16.
// grid = A*S*4: one wg per (ki, bg); each wg handles 16 b's.
__global__ __launch_bounds__(256) void k_trans(const float* __restrict__ w,
                                               const float* __restrict__ wofs,
                                               const float* __restrict__ z,
                                               __half* __restrict__ trans) {
  const int ki = blockIdx.x >> 2;
  const int bg = blockIdx.x & 3;
  const int j = threadIdx.x;
  const int lane = j & 63;
  const int wid = j >> 6;
  const float wbase = w[(size_t)ki * DS + j];
  const float4* wrow4 = reinterpret_cast<const float4*>(wofs + ((size_t)ki * DS + j) * DHY);
  const float4* z4 = reinterpret_cast<const float4*>(z);
  __shared__ float red[4][16];

  float acc[16];
  #pragma unroll
  for (int b = 0; b < 16; ++b) acc[b] = wbase;
  #pragma unroll
  for (int hc = 0; hc < 4; ++hc) {
    const float4 wa = wrow4[hc * 4 + 0];
    const float4 wb = wrow4[hc * 4 + 1];
    const float4 wc = wrow4[hc * 4 + 2];
    const float4 wd = wrow4[hc * 4 + 3];
    #pragma unroll
    for (int b = 0; b < 16; ++b) {
      const int zi = (bg * 16 + b) * 16 + hc * 4;  // float4 index into z (wave-uniform)
      const float4 za = z4[zi + 0];
      const float4 zb = z4[zi + 1];
      const float4 zc = z4[zi + 2];
      const float4 zd = z4[zi + 3];
      float a = acc[b];
      a = fmaf(za.x, wa.x, a); a = fmaf(za.y, wa.y, a);
      a = fmaf(za.z, wa.z, a); a = fmaf(za.w, wa.w, a);
      a = fmaf(zb.x, wb.x, a); a = fmaf(zb.y, wb.y, a);
      a = fmaf(zb.z, wb.z, a); a = fmaf(zb.w, wb.w, a);
      a = fmaf(zc.x, wc.x, a); a = fmaf(zc.y, wc.y, a);
      a = fmaf(zc.z, wc.z, a); a = fmaf(zc.w, wc.w, a);
      a = fmaf(zd.x, wd.x, a); a = fmaf(zd.y, wd.y, a);
      a = fmaf(zd.z, wd.z, a); a = fmaf(zd.w, wd.w, a);
      acc[b] = a;
    }
  }
  #pragma unroll
  for (int b = 0; b < 16; ++b) acc[b] = __expf(acc[b]);
  #pragma unroll
  for (int b = 0; b < 16; ++b) {
    float v = acc[b];
    #pragma unroll
    for (int o = 32; o >= 1; o >>= 1) v += __shfl_xor(v, o, 64);
    if (lane == 0) red[wid][b] = v;
  }
  __syncthreads();
  #pragma unroll
  for (int b = 0; b < 16; ++b) {
    const float s = red[0][b] + red[1][b] + red[2][b] + red[3][b];
    trans[(size_t)(bg * 16 + b) * (DA * DS * DS) + (size_t)ki * DS + j] =
        __float2half(acc[b] / s);
  }
}

// ---------------- persistent scan, L2-resident trans ----------------
// grid = 256 wgs: x = wgid&7 (XCD under %8 round-robin), jt = (wgid>>3)&15 (j-chunk of 16),
// pp = wgid>>7 (0..1). Each wg group of 16 (same b) runs 4 sequential full scans:
// pass p handles b = x + 8*pp + 16*p. Per XCD: 2 concurrent b -> trans slice 4 MB = L2.
// Cross-wg handoff: s_buf/cnt via RELAXED agent-scope atomics (bypass L2, MALL-mediated;
// correct for ANY wg->XCD mapping). NO acquire fences anywhere -> L2 trans lines survive.
union HV { int4 i4; __half2 h2[4]; };

#define S_LD(I) (*reinterpret_cast<const int4*>(tb + (size_t)((I) * 128 + rw) * DS))
#define S_FMA(QV, I) {                                              \
    HV u; u.i4 = (QV);                                              \
    const float wgt = wv[(I) * 128 + rw];                           \
    const float2 f0 = __half22float2(u.h2[0]);                      \
    const float2 f1 = __half22float2(u.h2[1]);                      \
    const float2 f2 = __half22float2(u.h2[2]);                      \
    const float2 f3 = __half22float2(u.h2[3]);                      \
    acc[0] = fmaf(wgt, f0.x, acc[0]); acc[1] = fmaf(wgt, f0.y, acc[1]); \
    acc[2] = fmaf(wgt, f1.x, acc[2]); acc[3] = fmaf(wgt, f1.y, acc[3]); \
    acc[4] = fmaf(wgt, f2.x, acc[4]); acc[5] = fmaf(wgt, f2.y, acc[5]); \
    acc[6] = fmaf(wgt, f3.x, acc[6]); acc[7] = fmaf(wgt, f3.y, acc[7]); }

__global__ __launch_bounds__(256, 2) void k_scan(
    const __half* __restrict__ trans,
    const float* __restrict__ logp_o,
    const float* __restrict__ logp_u,
    const __half* __restrict__ value16,
    const float* __restrict__ h_dist,
    const float* __restrict__ b0,
    float* __restrict__ s_buf,          // [2][B][S], accessed via relaxed atomics
    unsigned int* __restrict__ cnt,     // [B], zeroed by k_zero
    float* __restrict__ out_b,
    float* __restrict__ out_pi) {
  const int x  = blockIdx.x & 7;
  const int jt = (blockIdx.x >> 3) & 15;
  const int pp = blockIdx.x >> 7;
  const int tid = threadIdx.x;
  const int lane = tid & 63;
  const int wid = tid >> 6;

  __shared__ __align__(16) float wv[DA * DS];  // 16 KB
  __shared__ __align__(16) float bl[DS];
  __shared__ float aa[DA];
  __shared__ float redm[4], reds[4];
  __shared__ float red4[4][2][8];
  __shared__ float api[DA];

  const int jh = tid & 1;        // 8-j half within the 16-j chunk
  const int rw = tid >> 1;       // 128 rows per pass over (k,i)

  for (int p = 0; p < 4; ++p) {
    const int bb = x + 8 * pp + 16 * p;
    const __half* tb = trans + (size_t)bb * (DA * DS * DS) + jt * 16 + jh * 8;
    bl[tid] = b0[bb * DS + tid];
    __syncthreads();

    for (int t = 0; t < DT; ++t) {
      // ---- alpha_a ----
      if (tid < DA) {
        const float lg = logp_u[((size_t)t * DB + bb) * DA + tid];
        float m = lg;
        #pragma unroll
        for (int o = 8; o >= 1; o >>= 1) m = fmaxf(m, __shfl_xor(m, o, 16));
        const float e = __expf(lg - m);
        float s = e;
        #pragma unroll
        for (int o = 8; o >= 1; o >>= 1) s += __shfl_xor(s, o, 16);
        aa[tid] = e / s;
      }
      __syncthreads();
      #pragma unroll
      for (int r = tid; r < DA * DS; r += 256) wv[r] = aa[r >> 8] * bl[r & 255];
      __syncthreads();

      // ---- phase A: s_next partial for 16 j's over all 4096 rows (L2-resident trans) ----
      float acc[8] = {0.f, 0.f, 0.f, 0.f, 0.f, 0.f, 0.f, 0.f};
      {
        int4 Q0 = S_LD(0), Q1 = S_LD(1), Q2 = S_LD(2), Q3 = S_LD(3);
        int4 Q4 = S_LD(4), Q5 = S_LD(5), Q6 = S_LD(6), Q7 = S_LD(7);
        #pragma unroll
        for (int it = 0; it < 24; it += 8) {
          S_FMA(Q0, it + 0); Q0 = S_LD(it + 8);
          S_FMA(Q1, it + 1); Q1 = S_LD(it + 9);
          S_FMA(Q2, it + 2); Q2 = S_LD(it + 10);
          S_FMA(Q3, it + 3); Q3 = S_LD(it + 11);
          S_FMA(Q4, it + 4); Q4 = S_LD(it + 12);
          S_FMA(Q5, it + 5); Q5 = S_LD(it + 13);
          S_FMA(Q6, it + 6); Q6 = S_LD(it + 14);
          S_FMA(Q7, it + 7); Q7 = S_LD(it + 15);
        }
        S_FMA(Q0, 24); S_FMA(Q1, 25); S_FMA(Q2, 26); S_FMA(Q3, 27);
        S_FMA(Q4, 28); S_FMA(Q5, 29); S_FMA(Q6, 30); S_FMA(Q7, 31);
      }
      #pragma unroll
      for (int q = 0; q < 8; ++q) {  // reduce over row lanes (bits 1..5)
        acc[q] += __shfl_xor(acc[q], 2, 64);
        acc[q] += __shfl_xor(acc[q], 4, 64);
        acc[q] += __shfl_xor(acc[q], 8, 64);
        acc[q] += __shfl_xor(acc[q], 16, 64);
        acc[q] += __shfl_xor(acc[q], 32, 64);
      }
      if (lane < 2) {
        #pragma unroll
        for (int q = 0; q < 8; ++q) red4[wid][lane][q] = acc[q];
      }
      __syncthreads();
      if (tid < 16) {
        const int jh2 = tid >> 3, q2 = tid & 7;
        const float s = red4[0][jh2][q2] + red4[1][jh2][q2] +
                        red4[2][jh2][q2] + red4[3][jh2][q2];
        __hip_atomic_store(&s_buf[(size_t)(t & 1) * DB * DS + bb * DS + jt * 16 + jh2 * 8 + q2],
                           s, __ATOMIC_RELAXED, __HIP_MEMORY_SCOPE_AGENT);
      }
      __syncthreads();  // drains vmcnt for the whole wg
      if (tid == 0) {
        __hip_atomic_fetch_add(&cnt[bb], 1u, __ATOMIC_RELEASE, __HIP_MEMORY_SCOPE_AGENT);
        const unsigned int target = 16u * (unsigned int)(t + 1);
        while (__hip_atomic_load(&cnt[bb], __ATOMIC_RELAXED, __HIP_MEMORY_SCOPE_AGENT) < target)
          __builtin_amdgcn_s_sleep(2);
      }
      __syncthreads();

      // ---- belief update (redundant per wg); s_buf via relaxed atomics (MALL) ----
      const float sv = __hip_atomic_load(&s_buf[(size_t)(t & 1) * DB * DS + bb * DS + tid],
                                         __ATOMIC_RELAXED, __HIP_MEMORY_SCOPE_AGENT);
      const float l = __logf(sv + 1e-6f) + logp_o[((size_t)t * DB + bb) * DS + tid];
      float m = l;
      #pragma unroll
      for (int o = 32; o >= 1; o >>= 1) m = fmaxf(m, __shfl_xor(m, o, 64));
      if (lane == 0) redm[wid] = m;
      __syncthreads();
      m = fmaxf(fmaxf(redm[0], redm[1]), fmaxf(redm[2], redm[3]));
      const float e = __expf(l - m);
      float v = e;
      #pragma unroll
      for (int o = 32; o >= 1; o >>= 1) v += __shfl_xor(v, o, 64);
      if (lane == 0) reds[wid] = v;
      if (tid < DA) api[tid] = 0.f;
      __syncthreads();
      const float pbl = e / (reds[0] + reds[1] + reds[2] + reds[3]);
      bl[tid] = pbl;
      if (jt == 0) out_b[((size_t)t * DB + bb) * DS + tid] = pbl;
      __syncthreads();

      // ---- plan for step t: wgs jt<8 handle h = jt*4 + wid (guard h<30) ----
      const int h = jt * 4 + wid;
      const int k = lane >> 2;
      const int q = lane & 3;
      float dot = 0.f;
      if (h < DH) {
        const __half* vr = value16 + (((size_t)h * DB + bb) * DA + k) * DS + q * 64;
        const float* blq = bl + q * 64;
        #pragma unroll
        for (int ii = 0; ii < 64; ii += 8) {
          HV u;
          u.i4 = *reinterpret_cast<const int4*>(vr + ii);
          const float4 c0 = *reinterpret_cast<const float4*>(blq + ii);
          const float4 c1 = *reinterpret_cast<const float4*>(blq + ii + 4);
          const float2 f0 = __half22float2(u.h2[0]);
          const float2 f1 = __half22float2(u.h2[1]);
          const float2 f2 = __half22float2(u.h2[2]);
          const float2 f3 = __half22float2(u.h2[3]);
          dot = fmaf(f0.x, c0.x, dot); dot = fmaf(f0.y, c0.y, dot);
          dot = fmaf(f1.x, c0.z, dot); dot = fmaf(f1.y, c0.w, dot);
          dot = fmaf(f2.x, c1.x, dot); dot = fmaf(f2.y, c1.y, dot);
          dot = fmaf(f3.x, c1.z, dot); dot = fmaf(f3.y, c1.w, dot);
        }
        dot += __shfl_xor(dot, 1, 64);   // combine quarters
        dot += __shfl_xor(dot, 2, 64);
        float mk = dot;                   // softmax over k (lane bits 2..5)
        #pragma unroll
        for (int o = 4; o <= 32; o <<= 1) mk = fmaxf(mk, __shfl_xor(mk, o, 64));
        const float ek = __expf(dot - mk);
        float sk = ek;
        #pragma unroll
        for (int o = 4; o <= 32; o <<= 1) sk += __shfl_xor(sk, o, 64);
        if (q == 0) atomicAdd(&api[k], (ek / sk) * h_dist[bb * DH + h]);
      }
      __syncthreads();
      if (jt < 8 && tid < DA)
        atomicAdd(&out_pi[((size_t)t * DB + bb) * DA + tid], api[tid]);
      __syncthreads();
    }
  }
}

// ---------------- launch ----------------

extern "C" void kernel_launch(void* const* d_in, const int* in_sizes, int n_in,
                              void* d_out, int out_size, void* d_ws, size_t ws_size,
                              hipStream_t stream) {
  const float* logp_o = (const float*)d_in[0];
  const float* logp_u = (const float*)d_in[1];
  const float* value  = (const float*)d_in[2];
  const float* z      = (const float*)d_in[3];
  const float* b0     = (const float*)d_in[4];
  const float* w      = (const float*)d_in[5];
  const float* wofs   = (const float*)d_in[6];
  const float* tau    = (const float*)d_in[7];
  const float* tauw   = (const float*)d_in[8];

  char* ws = (char*)d_ws;
  size_t off = 0;
  __half* trans      = (__half*)(ws + off);       off += (size_t)DB * DA * DS * DS * sizeof(__half);
  float* s_buf       = (float*)(ws + off);        off += (size_t)2 * DB * DS * sizeof(float);
  unsigned int* cnt  = (unsigned int*)(ws + off); off += 256;
  __half* value16    = (__half*)(ws + off);       off += (size_t)DH * DB * DA * DS * sizeof(__half);
  float* h_dist      = (float*)(ws + off);        off += (size_t)DB * DH * sizeof(float) + 64;
  if (off > ws_size) return;

  float* out_b  = (float*)d_out;
  float* out_pi = out_b + (size_t)DT * DB * DS;

  k_zero<<<256, 256, 0, stream>>>(out_pi, cnt);
  k_hdist<<<1, 64, 0, stream>>>(z, tau, tauw, h_dist);
  k_vconv<<<1024, 256, 0, stream>>>(value, value16, DH * DB * DA * DS / 4);
  k_trans<<<DA * DS * 4, 256, 0, stream>>>(w, wofs, z, trans);
  k_scan<<<256, 256, 0, stream>>>(trans, logp_o, logp_u, value16, h_dist, b0,
                                  s_buf, cnt, out_b, out_pi);
}

// Round 7
// 1492.344 us; speedup vs baseline: 3.8607x; 3.8607x over previous
//
#include <hip/hip_runtime.h>
#include <hip/hip_fp16.h>

#define DS 256   // state_dim
#define DA 16    // act_dim
#define DH 30    // horizon
#define DHY 64   // hyper_dim
#define DB 64    // batch
#define DT 64    // seq len

union HV  { int4 i4; __half2 h2[4]; };
union HV2 { int2 i2; __half2 h2[2]; };

// ---------------- setup kernels ----------------

__global__ __launch_bounds__(64) void k_hdist(const float* __restrict__ z,
                                              const float* __restrict__ tau,
                                              const float* __restrict__ tauw,
                                              float* __restrict__ h_dist) {
  const int bb = threadIdx.x;
  if (bb >= DB) return;
  float x = tau[0];
  for (int hy = 0; hy < DHY; ++hy) x = fmaf(z[bb * DHY + hy], tauw[hy], x);
  x = fminf(fmaxf(x, -8.f), 8.f);
  const float rate = __expf(x);
  const float lr = x;
  float lp[DH];
  float lg = 0.f;
  float mx = -1e30f;
  #pragma unroll
  for (int h = 0; h < DH; ++h) {
    const float ks = (float)(h + 1);
    lg += __logf(ks);
    lp[h] = ks * lr - rate - lg;
    mx = fmaxf(mx, lp[h]);
  }
  float sum = 0.f;
  #pragma unroll
  for (int h = 0; h < DH; ++h) { lp[h] = __expf(lp[h] - mx); sum += lp[h]; }
  const float inv = 1.f / sum;
  #pragma unroll
  for (int h = 0; h < DH; ++h) h_dist[bb * DH + h] = lp[h] * inv;
}

// alpha_a = softmax(logp_u) over A. rows = T*B = 4096, 16 rows per wg.
__global__ __launch_bounds__(256) void k_alpha(const float* __restrict__ logp_u,
                                               float* __restrict__ alpha_a) {
  const int row = blockIdx.x * 16 + (threadIdx.x >> 4);
  const int k = threadIdx.x & 15;
  const float v = logp_u[(size_t)row * DA + k];
  float m = v;
  #pragma unroll
  for (int o = 8; o >= 1; o >>= 1) m = fmaxf(m, __shfl_xor(m, o, 16));
  const float e = __expf(v - m);
  float s = e;
  #pragma unroll
  for (int o = 8; o >= 1; o >>= 1) s += __shfl_xor(s, o, 16);
  alpha_a[(size_t)row * DA + k] = e / s;
}

__global__ __launch_bounds__(256) void k_zero(float* __restrict__ out_pi) {
  out_pi[blockIdx.x * 256 + threadIdx.x] = 0.f;
}

// value fp32 -> fp16 (n4 = DH*DB*DA*DS/4)
__global__ __launch_bounds__(256) void k_vconv(const float* __restrict__ v,
                                               __half* __restrict__ v16, int n4) {
  const int stride = gridDim.x * 256;
  for (int i = blockIdx.x * 256 + threadIdx.x; i < n4; i += stride) {
    const float4 f = reinterpret_cast<const float4*>(v)[i];
    reinterpret_cast<__half2*>(v16)[2 * i]     = __floats2half2_rn(f.x, f.y);
    reinterpret_cast<__half2*>(v16)[2 * i + 1] = __floats2half2_rn(f.z, f.w);
  }
}

// transition[b,k,i,j] = softmax_j(w[(k,i),j] + z[b]·wofs[(k,i,j),:]), fp16.
// grid = A*S*4: one wg per (ki, bg of 16 b).
__global__ __launch_bounds__(256) void k_trans(const float* __restrict__ w,
                                               const float* __restrict__ wofs,
                                               const float* __restrict__ z,
                                               __half* __restrict__ trans) {
  const int ki = blockIdx.x >> 2;
  const int bg = blockIdx.x & 3;
  const int j = threadIdx.x;
  const int lane = j & 63;
  const int wid = j >> 6;
  const float wbase = w[(size_t)ki * DS + j];
  const float4* wrow4 = reinterpret_cast<const float4*>(wofs + ((size_t)ki * DS + j) * DHY);
  const float4* z4 = reinterpret_cast<const float4*>(z);
  __shared__ float red[4][16];

  float acc[16];
  #pragma unroll
  for (int b = 0; b < 16; ++b) acc[b] = wbase;
  #pragma unroll
  for (int hc = 0; hc < 4; ++hc) {
    const float4 wa = wrow4[hc * 4 + 0];
    const float4 wb = wrow4[hc * 4 + 1];
    const float4 wc = wrow4[hc * 4 + 2];
    const float4 wd = wrow4[hc * 4 + 3];
    #pragma unroll
    for (int b = 0; b < 16; ++b) {
      const int zi = (bg * 16 + b) * 16 + hc * 4;
      const float4 za = z4[zi + 0];
      const float4 zb = z4[zi + 1];
      const float4 zc = z4[zi + 2];
      const float4 zd = z4[zi + 3];
      float a = acc[b];
      a = fmaf(za.x, wa.x, a); a = fmaf(za.y, wa.y, a);
      a = fmaf(za.z, wa.z, a); a = fmaf(za.w, wa.w, a);
      a = fmaf(zb.x, wb.x, a); a = fmaf(zb.y, wb.y, a);
      a = fmaf(zb.z, wb.z, a); a = fmaf(zb.w, wb.w, a);
      a = fmaf(zc.x, wc.x, a); a = fmaf(zc.y, wc.y, a);
      a = fmaf(zc.z, wc.z, a); a = fmaf(zc.w, wc.w, a);
      a = fmaf(zd.x, wd.x, a); a = fmaf(zd.y, wd.y, a);
      a = fmaf(zd.z, wd.z, a); a = fmaf(zd.w, wd.w, a);
      acc[b] = a;
    }
  }
  #pragma unroll
  for (int b = 0; b < 16; ++b) acc[b] = __expf(acc[b]);
  #pragma unroll
  for (int b = 0; b < 16; ++b) {
    float v = acc[b];
    #pragma unroll
    for (int o = 32; o >= 1; o >>= 1) v += __shfl_xor(v, o, 64);
    if (lane == 0) red[wid][b] = v;
  }
  __syncthreads();
  #pragma unroll
  for (int b = 0; b < 16; ++b) {
    const float s = red[0][b] + red[1][b] + red[2][b] + red[3][b];
    trans[(size_t)(bg * 16 + b) * (DA * DS * DS) + (size_t)ki * DS + j] =
        __float2half(acc[b] / s);
  }
}

// ---------------- M precompute: M[tt,b,i,j] = sum_k alpha_a[t0+tt,b,k] * T[b,k,i,j] ----------------
// grid = 64 b x 16 i-chunks. Thread: lane -> 4 j's, wave -> i. fp16 out.
__global__ __launch_bounds__(256) void k_mbuild(const __half* __restrict__ trans,
                                                const float* __restrict__ alpha_a,
                                                __half* __restrict__ Mch,
                                                int t0, int TC) {
  const int b = blockIdx.x >> 4;
  const int ich = (blockIdx.x & 15) << 4;
  const int tid = threadIdx.x;
  const int lane = tid & 63;
  const int wid = tid >> 6;
  __shared__ float a_lds[32 * DA];  // TC <= 32
  for (int r = tid; r < TC * DA; r += 256)
    a_lds[r] = alpha_a[((size_t)(t0 + (r >> 4)) * DB + b) * DA + (r & 15)];
  __syncthreads();
  for (int io = 0; io < 4; ++io) {
    const int i = ich + io * 4 + wid;
    const __half* tp = trans + ((size_t)b * DA * DS + i) * DS + lane * 4;
    float Tf[64];
    #pragma unroll
    for (int k = 0; k < 16; ++k) {
      HV2 u;
      u.i2 = *reinterpret_cast<const int2*>(tp + (size_t)k * (DS * DS));
      const float2 f0 = __half22float2(u.h2[0]);
      const float2 f1 = __half22float2(u.h2[1]);
      Tf[k * 4 + 0] = f0.x; Tf[k * 4 + 1] = f0.y;
      Tf[k * 4 + 2] = f1.x; Tf[k * 4 + 3] = f1.y;
    }
    for (int tt = 0; tt < TC; ++tt) {
      float m0 = 0.f, m1 = 0.f, m2 = 0.f, m3 = 0.f;
      #pragma unroll
      for (int k = 0; k < 16; ++k) {
        const float ak = a_lds[tt * DA + k];
        m0 = fmaf(ak, Tf[k * 4 + 0], m0);
        m1 = fmaf(ak, Tf[k * 4 + 1], m1);
        m2 = fmaf(ak, Tf[k * 4 + 2], m2);
        m3 = fmaf(ak, Tf[k * 4 + 3], m3);
      }
      HV2 o;
      o.h2[0] = __floats2half2_rn(m0, m1);
      o.h2[1] = __floats2half2_rn(m2, m3);
      *reinterpret_cast<int2*>(Mch + (((size_t)tt * DB + b) * DS + i) * DS + lane * 4) = o.i2;
    }
  }
}

// ---------------- scan chunk: one wg per b, TC steps, zero cross-wg traffic ----------------
__global__ __launch_bounds__(256) void k_scanchunk(const __half* __restrict__ Mch,
                                                   const float* __restrict__ logp_o,
                                                   const float* __restrict__ b0,
                                                   float* __restrict__ bl_buf,
                                                   float* __restrict__ out_b,
                                                   int t0, int TC) {
  const int b = blockIdx.x;
  const int tid = threadIdx.x;
  const int lane = tid & 63;
  const int wid = tid >> 6;
  __shared__ __align__(16) float bl[DS];
  __shared__ float red4[4][32][8];
  __shared__ float redm[4], reds[4];
  bl[tid] = (t0 == 0) ? b0[b * DS + tid] : bl_buf[b * DS + tid];
  __syncthreads();
  const int jg = tid & 31;   // 8 j's: j = jg*8 + q
  const int rw = tid >> 5;   // i stride 8
  for (int tt = 0; tt < TC; ++tt) {
    const int t = t0 + tt;
    // s_next[j] = sum_i bl[i] * M[tt][b][i][j]
    const __half* mb = Mch + ((size_t)tt * DB + b) * (DS * DS) + jg * 8;
    float acc[8] = {0.f, 0.f, 0.f, 0.f, 0.f, 0.f, 0.f, 0.f};
    #pragma unroll 16
    for (int it = 0; it < 32; ++it) {
      const int i = it * 8 + rw;
      HV u;
      u.i4 = *reinterpret_cast<const int4*>(mb + (size_t)i * DS);
      const float wgt = bl[i];
      const float2 f0 = __half22float2(u.h2[0]);
      const float2 f1 = __half22float2(u.h2[1]);
      const float2 f2 = __half22float2(u.h2[2]);
      const float2 f3 = __half22float2(u.h2[3]);
      acc[0] = fmaf(wgt, f0.x, acc[0]); acc[1] = fmaf(wgt, f0.y, acc[1]);
      acc[2] = fmaf(wgt, f1.x, acc[2]); acc[3] = fmaf(wgt, f1.y, acc[3]);
      acc[4] = fmaf(wgt, f2.x, acc[4]); acc[5] = fmaf(wgt, f2.y, acc[5]);
      acc[6] = fmaf(wgt, f3.x, acc[6]); acc[7] = fmaf(wgt, f3.y, acc[7]);
    }
    #pragma unroll
    for (int q = 0; q < 8; ++q) acc[q] += __shfl_xor(acc[q], 32, 64);
    if (lane < 32) {
      #pragma unroll
      for (int q = 0; q < 8; ++q) red4[wid][lane][q] = acc[q];
    }
    __syncthreads();
    const int jj = tid >> 3, qq = tid & 7;
    const float sv = red4[0][jj][qq] + red4[1][jj][qq] + red4[2][jj][qq] + red4[3][jj][qq];
    // belief update
    const float l = __logf(sv + 1e-6f) + logp_o[((size_t)t * DB + b) * DS + tid];
    float m = l;
    #pragma unroll
    for (int o = 32; o >= 1; o >>= 1) m = fmaxf(m, __shfl_xor(m, o, 64));
    if (lane == 0) redm[wid] = m;
    __syncthreads();
    m = fmaxf(fmaxf(redm[0], redm[1]), fmaxf(redm[2], redm[3]));
    const float e = __expf(l - m);
    float v = e;
    #pragma unroll
    for (int o = 32; o >= 1; o >>= 1) v += __shfl_xor(v, o, 64);
    if (lane == 0) reds[wid] = v;
    __syncthreads();
    const float p = e / (reds[0] + reds[1] + reds[2] + reds[3]);
    bl[tid] = p;
    out_b[((size_t)t * DB + b) * DS + tid] = p;
    __syncthreads();
  }
  bl_buf[b * DS + tid] = bl[tid];
}

// ---------------- plan mega-kernel: grid = T*B wgs, reads out_b, writes out_pi ----------------
__global__ __launch_bounds__(256) void k_planall(const float* __restrict__ out_b,
                                                 const __half* __restrict__ value16,
                                                 const float* __restrict__ h_dist,
                                                 float* __restrict__ out_pi) {
  const int b = blockIdx.x & 63;
  const int t = blockIdx.x >> 6;
  const int tid = threadIdx.x;
  const int lane = tid & 63;
  const int wid = tid >> 6;
  __shared__ __align__(16) float bl[DS];
  __shared__ float api[DA];
  bl[tid] = out_b[((size_t)t * DB + b) * DS + tid];
  if (tid < DA) api[tid] = 0.f;
  __syncthreads();
  const int k = lane >> 2;
  const int q = lane & 3;
  for (int p = 0; p < 8; ++p) {
    const int h = p * 4 + wid;
    if (h < DH) {
      const __half* vr = value16 + (((size_t)h * DB + b) * DA + k) * DS + q * 64;
      const float* blq = bl + q * 64;
      float dot = 0.f;
      #pragma unroll
      for (int ii = 0; ii < 64; ii += 8) {
        HV u;
        u.i4 = *reinterpret_cast<const int4*>(vr + ii);
        const float4 c0 = *reinterpret_cast<const float4*>(blq + ii);
        const float4 c1 = *reinterpret_cast<const float4*>(blq + ii + 4);
        const float2 f0 = __half22float2(u.h2[0]);
        const float2 f1 = __half22float2(u.h2[1]);
        const float2 f2 = __half22float2(u.h2[2]);
        const float2 f3 = __half22float2(u.h2[3]);
        dot = fmaf(f0.x, c0.x, dot); dot = fmaf(f0.y, c0.y, dot);
        dot = fmaf(f1.x, c0.z, dot); dot = fmaf(f1.y, c0.w, dot);
        dot = fmaf(f2.x, c1.x, dot); dot = fmaf(f2.y, c1.y, dot);
        dot = fmaf(f3.x, c1.z, dot); dot = fmaf(f3.y, c1.w, dot);
      }
      dot += __shfl_xor(dot, 1, 64);
      dot += __shfl_xor(dot, 2, 64);
      float mk = dot;
      #pragma unroll
      for (int o = 4; o <= 32; o <<= 1) mk = fmaxf(mk, __shfl_xor(mk, o, 64));
      const float ek = __expf(dot - mk);
      float sk = ek;
      #pragma unroll
      for (int o = 4; o <= 32; o <<= 1) sk += __shfl_xor(sk, o, 64);
      if (q == 0) atomicAdd(&api[k], (ek / sk) * h_dist[b * DH + h]);
    }
  }
  __syncthreads();
  if (tid < DA) out_pi[((size_t)t * DB + b) * DA + tid] = api[tid];
}

// ---------------- fallback per-step kernel (R5) for small ws ----------------
#define K_LD(I) (*reinterpret_cast<const int4*>(tb + (size_t)((I) * 64 + rb) * DS))
#define K_FMA(QV, I) {                                              \
    HV u; u.i4 = (QV);                                              \
    const float wgt = wv[(I) * 64 + rb];                            \
    const float2 f0 = __half22float2(u.h2[0]);                      \
    const float2 f1 = __half22float2(u.h2[1]);                      \
    const float2 f2 = __half22float2(u.h2[2]);                      \
    const float2 f3 = __half22float2(u.h2[3]);                      \
    acc[0] = fmaf(wgt, f0.x, acc[0]); acc[1] = fmaf(wgt, f0.y, acc[1]); \
    acc[2] = fmaf(wgt, f1.x, acc[2]); acc[3] = fmaf(wgt, f1.y, acc[3]); \
    acc[4] = fmaf(wgt, f2.x, acc[4]); acc[5] = fmaf(wgt, f2.y, acc[5]); \
    acc[6] = fmaf(wgt, f3.x, acc[6]); acc[7] = fmaf(wgt, f3.y, acc[7]); }

__global__ __launch_bounds__(256, 2) void k_step(
    const __half* __restrict__ trans, const float* __restrict__ logp_o,
    const float* __restrict__ logp_u, const __half* __restrict__ value16,
    const float* __restrict__ h_dist, const float* __restrict__ b0,
    float* __restrict__ s_buf, float* __restrict__ out_b,
    float* __restrict__ out_pi, int t) {
  const int bb = blockIdx.x & 63;
  const int jt = blockIdx.x >> 6;
  const int tid = threadIdx.x;
  const int lane = tid & 63;
  const int wid = tid >> 6;
  __shared__ __align__(16) float wv[DA * DS];
  __shared__ __align__(16) float bl[DS];
  __shared__ float aa[DA];
  __shared__ float redm[4], reds[4];
  __shared__ float red4[4][4][8];
  __shared__ float api[DA];
  if (t > 0) {
    const int tp = t - 1;
    const float sv = s_buf[(size_t)(tp & 1) * DB * DS + bb * DS + tid];
    const float l = __logf(sv + 1e-6f) + logp_o[((size_t)tp * DB + bb) * DS + tid];
    float m = l;
    #pragma unroll
    for (int o = 32; o >= 1; o >>= 1) m = fmaxf(m, __shfl_xor(m, o, 64));
    if (lane == 0) redm[wid] = m;
    __syncthreads();
    m = fmaxf(fmaxf(redm[0], redm[1]), fmaxf(redm[2], redm[3]));
    const float e = __expf(l - m);
    float v = e;
    #pragma unroll
    for (int o = 32; o >= 1; o >>= 1) v += __shfl_xor(v, o, 64);
    if (lane == 0) reds[wid] = v;
    if (tid < DA) api[tid] = 0.f;
    __syncthreads();
    const float p = e / (reds[0] + reds[1] + reds[2] + reds[3]);
    bl[tid] = p;
    if (jt == 0) out_b[((size_t)tp * DB + bb) * DS + tid] = p;
    __syncthreads();
    const int h = jt * 4 + wid;
    const int k = lane >> 2;
    const int q = lane & 3;
    if (h < DH) {
      const __half* vr = value16 + (((size_t)h * DB + bb) * DA + k) * DS + q * 64;
      const float* blq = bl + q * 64;
      float dot = 0.f;
      #pragma unroll
      for (int ii = 0; ii < 64; ii += 8) {
        HV u;
        u.i4 = *reinterpret_cast<const int4*>(vr + ii);
        const float4 c0 = *reinterpret_cast<const float4*>(blq + ii);
        const float4 c1 = *reinterpret_cast<const float4*>(blq + ii + 4);
        const float2 f0 = __half22float2(u.h2[0]);
        const float2 f1 = __half22float2(u.h2[1]);
        const float2 f2 = __half22float2(u.h2[2]);
        const float2 f3 = __half22float2(u.h2[3]);
        dot = fmaf(f0.x, c0.x, dot); dot = fmaf(f0.y, c0.y, dot);
        dot = fmaf(f1.x, c0.z, dot); dot = fmaf(f1.y, c0.w, dot);
        dot = fmaf(f2.x, c1.x, dot); dot = fmaf(f2.y, c1.y, dot);
        dot = fmaf(f3.x, c1.z, dot); dot = fmaf(f3.y, c1.w, dot);
      }
      dot += __shfl_xor(dot, 1, 64);
      dot += __shfl_xor(dot, 2, 64);
      float mk = dot;
      #pragma unroll
      for (int o = 4; o <= 32; o <<= 1) mk = fmaxf(mk, __shfl_xor(mk, o, 64));
      const float ek = __expf(dot - mk);
      float sk = ek;
      #pragma unroll
      for (int o = 4; o <= 32; o <<= 1) sk += __shfl_xor(sk, o, 64);
      if (q == 0) atomicAdd(&api[k], (ek / sk) * h_dist[bb * DH + h]);
    }
    __syncthreads();
    if (tid < DA) atomicAdd(&out_pi[((size_t)tp * DB + bb) * DA + tid], api[tid]);
  } else {
    bl[tid] = b0[bb * DS + tid];
  }
  __syncthreads();
  if (t < DT) {
    if (tid < DA) {
      const float lg = logp_u[((size_t)t * DB + bb) * DA + tid];
      float m = lg;
      #pragma unroll
      for (int o = 8; o >= 1; o >>= 1) m = fmaxf(m, __shfl_xor(m, o, 16));
      const float e = __expf(lg - m);
      float s = e;
      #pragma unroll
      for (int o = 8; o >= 1; o >>= 1) s += __shfl_xor(s, o, 16);
      aa[tid] = e / s;
    }
    __syncthreads();
    #pragma unroll
    for (int r = tid; r < DA * DS; r += 256) wv[r] = aa[r >> 8] * bl[r & 255];
    __syncthreads();
    const int jg = tid & 3;
    const int rb = tid >> 2;
    const __half* tb = trans + (size_t)bb * (DA * DS * DS) + jt * 32 + jg * 8;
    float acc[8] = {0.f, 0.f, 0.f, 0.f, 0.f, 0.f, 0.f, 0.f};
    int4 Q0 = K_LD(0), Q1 = K_LD(1), Q2 = K_LD(2), Q3 = K_LD(3);
    int4 Q4 = K_LD(4), Q5 = K_LD(5), Q6 = K_LD(6), Q7 = K_LD(7);
    #pragma unroll
    for (int it = 0; it < 56; it += 8) {
      K_FMA(Q0, it + 0); Q0 = K_LD(it + 8);
      K_FMA(Q1, it + 1); Q1 = K_LD(it + 9);
      K_FMA(Q2, it + 2); Q2 = K_LD(it + 10);
      K_FMA(Q3, it + 3); Q3 = K_LD(it + 11);
      K_FMA(Q4, it + 4); Q4 = K_LD(it + 12);
      K_FMA(Q5, it + 5); Q5 = K_LD(it + 13);
      K_FMA(Q6, it + 6); Q6 = K_LD(it + 14);
      K_FMA(Q7, it + 7); Q7 = K_LD(it + 15);
    }
    K_FMA(Q0, 56); K_FMA(Q1, 57); K_FMA(Q2, 58); K_FMA(Q3, 59);
    K_FMA(Q4, 60); K_FMA(Q5, 61); K_FMA(Q6, 62); K_FMA(Q7, 63);
    #pragma unroll
    for (int q = 0; q < 8; ++q) {
      acc[q] += __shfl_xor(acc[q], 4, 64);
      acc[q] += __shfl_xor(acc[q], 8, 64);
      acc[q] += __shfl_xor(acc[q], 16, 64);
      acc[q] += __shfl_xor(acc[q], 32, 64);
    }
    if (lane < 4) {
      #pragma unroll
      for (int q = 0; q < 8; ++q) red4[wid][lane][q] = acc[q];
    }
    __syncthreads();
    if (tid < 32) {
      const int jg2 = tid >> 3, q2 = tid & 7;
      const float s = red4[0][jg2][q2] + red4[1][jg2][q2] +
                      red4[2][jg2][q2] + red4[3][jg2][q2];
      s_buf[(size_t)(t & 1) * DB * DS + bb * DS + jt * 32 + jg2 * 8 + q2] = s;
    }
  }
}

// ---------------- launch ----------------

extern "C" void kernel_launch(void* const* d_in, const int* in_sizes, int n_in,
                              void* d_out, int out_size, void* d_ws, size_t ws_size,
                              hipStream_t stream) {
  const float* logp_o = (const float*)d_in[0];
  const float* logp_u = (const float*)d_in[1];
  const float* value  = (const float*)d_in[2];
  const float* z      = (const float*)d_in[3];
  const float* b0     = (const float*)d_in[4];
  const float* w      = (const float*)d_in[5];
  const float* wofs   = (const float*)d_in[6];
  const float* tau    = (const float*)d_in[7];
  const float* tauw   = (const float*)d_in[8];

  char* ws = (char*)d_ws;
  size_t off = 0;
  __half* trans   = (__half*)(ws + off); off += (size_t)DB * DA * DS * DS * sizeof(__half);
  __half* value16 = (__half*)(ws + off); off += (size_t)DH * DB * DA * DS * sizeof(__half);
  float* alpha_a  = (float*)(ws + off);  off += (size_t)DT * DB * DA * sizeof(float);
  float* s_buf    = (float*)(ws + off);  off += (size_t)2 * DB * DS * sizeof(float);
  float* bl_buf   = (float*)(ws + off);  off += (size_t)DB * DS * sizeof(float);
  float* h_dist   = (float*)(ws + off);  off += 8192;
  const size_t base = off;
  if (base > ws_size) return;
  __half* M = (__half*)(ws + base);
  const size_t m_per_t = (size_t)DB * DS * DS * sizeof(__half);  // 8,388,608 B
  int TC = 0;
  const int cands[6] = {32, 16, 8, 4, 2, 1};
  for (int c = 0; c < 6; ++c)
    if (base + (size_t)cands[c] * m_per_t <= ws_size) { TC = cands[c]; break; }

  float* out_b  = (float*)d_out;
  float* out_pi = out_b + (size_t)DT * DB * DS;

  k_hdist<<<1, 64, 0, stream>>>(z, tau, tauw, h_dist);
  k_vconv<<<1024, 256, 0, stream>>>(value, value16, DH * DB * DA * DS / 4);
  k_trans<<<DA * DS * 4, 256, 0, stream>>>(w, wofs, z, trans);

  if (TC) {
    k_alpha<<<256, 256, 0, stream>>>(logp_u, alpha_a);
    for (int c = 0; c < DT / TC; ++c) {
      k_mbuild<<<DB * 16, 256, 0, stream>>>(trans, alpha_a, M, c * TC, TC);
      k_scanchunk<<<DB, 256, 0, stream>>>(M, logp_o, b0, bl_buf, out_b, c * TC, TC);
    }
    k_planall<<<DT * DB, 256, 0, stream>>>(out_b, value16, h_dist, out_pi);
  } else {
    k_zero<<<256, 256, 0, stream>>>(out_pi);
    for (int t = 0; t <= DT; ++t) {
      k_step<<<512, 256, 0, stream>>>(trans, logp_o, logp_u, value16, h_dist, b0,
                                      s_buf, out_b, out_pi, t);
    }
  }
}

// Round 8
// 748.886 us; speedup vs baseline: 7.6935x; 1.9928x over previous
//
#include <hip/hip_runtime.h>
#include <hip/hip_fp16.h>

#define DS 256   // state_dim
#define DA 16    // act_dim
#define DH 30    // horizon
#define DHY 64   // hyper_dim
#define DB 64    // batch
#define DT 64    // seq len

union HV  { int4 i4; __half2 h2[4]; };
union HV2 { int2 i2; __half2 h2[2]; };

// ---------------- setup kernels ----------------

__global__ __launch_bounds__(64) void k_hdist(const float* __restrict__ z,
                                              const float* __restrict__ tau,
                                              const float* __restrict__ tauw,
                                              float* __restrict__ h_dist) {
  const int bb = threadIdx.x;
  if (bb >= DB) return;
  float x = tau[0];
  for (int hy = 0; hy < DHY; ++hy) x = fmaf(z[bb * DHY + hy], tauw[hy], x);
  x = fminf(fmaxf(x, -8.f), 8.f);
  const float rate = __expf(x);
  const float lr = x;
  float lp[DH];
  float lg = 0.f;
  float mx = -1e30f;
  #pragma unroll
  for (int h = 0; h < DH; ++h) {
    const float ks = (float)(h + 1);
    lg += __logf(ks);
    lp[h] = ks * lr - rate - lg;
    mx = fmaxf(mx, lp[h]);
  }
  float sum = 0.f;
  #pragma unroll
  for (int h = 0; h < DH; ++h) { lp[h] = __expf(lp[h] - mx); sum += lp[h]; }
  const float inv = 1.f / sum;
  #pragma unroll
  for (int h = 0; h < DH; ++h) h_dist[bb * DH + h] = lp[h] * inv;
}

// alpha_a = softmax(logp_u) over A. rows = T*B = 4096, 16 rows per wg.
__global__ __launch_bounds__(256) void k_alpha(const float* __restrict__ logp_u,
                                               float* __restrict__ alpha_a) {
  const int row = blockIdx.x * 16 + (threadIdx.x >> 4);
  const int k = threadIdx.x & 15;
  const float v = logp_u[(size_t)row * DA + k];
  float m = v;
  #pragma unroll
  for (int o = 8; o >= 1; o >>= 1) m = fmaxf(m, __shfl_xor(m, o, 16));
  const float e = __expf(v - m);
  float s = e;
  #pragma unroll
  for (int o = 8; o >= 1; o >>= 1) s += __shfl_xor(s, o, 16);
  alpha_a[(size_t)row * DA + k] = e / s;
}

__global__ __launch_bounds__(256) void k_zero(float* __restrict__ out_pi) {
  out_pi[blockIdx.x * 256 + threadIdx.x] = 0.f;
}

// value fp32 -> fp16 (n4 = DH*DB*DA*DS/4)
__global__ __launch_bounds__(256) void k_vconv(const float* __restrict__ v,
                                               __half* __restrict__ v16, int n4) {
  const int stride = gridDim.x * 256;
  for (int i = blockIdx.x * 256 + threadIdx.x; i < n4; i += stride) {
    const float4 f = reinterpret_cast<const float4*>(v)[i];
    reinterpret_cast<__half2*>(v16)[2 * i]     = __floats2half2_rn(f.x, f.y);
    reinterpret_cast<__half2*>(v16)[2 * i + 1] = __floats2half2_rn(f.z, f.w);
  }
}

// transition[b,k,i,j] = softmax_j(w[(k,i),j] + z[b]·wofs[(k,i,j),:]), fp16.
// grid = A*S*4: one wg per (ki, bg of 16 b).
__global__ __launch_bounds__(256) void k_trans(const float* __restrict__ w,
                                               const float* __restrict__ wofs,
                                               const float* __restrict__ z,
                                               __half* __restrict__ trans) {
  const int ki = blockIdx.x >> 2;
  const int bg = blockIdx.x & 3;
  const int j = threadIdx.x;
  const int lane = j & 63;
  const int wid = j >> 6;
  const float wbase = w[(size_t)ki * DS + j];
  const float4* wrow4 = reinterpret_cast<const float4*>(wofs + ((size_t)ki * DS + j) * DHY);
  const float4* z4 = reinterpret_cast<const float4*>(z);
  __shared__ float red[4][16];

  float acc[16];
  #pragma unroll
  for (int b = 0; b < 16; ++b) acc[b] = wbase;
  #pragma unroll
  for (int hc = 0; hc < 4; ++hc) {
    const float4 wa = wrow4[hc * 4 + 0];
    const float4 wb = wrow4[hc * 4 + 1];
    const float4 wc = wrow4[hc * 4 + 2];
    const float4 wd = wrow4[hc * 4 + 3];
    #pragma unroll
    for (int b = 0; b < 16; ++b) {
      const int zi = (bg * 16 + b) * 16 + hc * 4;
      const float4 za = z4[zi + 0];
      const float4 zb = z4[zi + 1];
      const float4 zc = z4[zi + 2];
      const float4 zd = z4[zi + 3];
      float a = acc[b];
      a = fmaf(za.x, wa.x, a); a = fmaf(za.y, wa.y, a);
      a = fmaf(za.z, wa.z, a); a = fmaf(za.w, wa.w, a);
      a = fmaf(zb.x, wb.x, a); a = fmaf(zb.y, wb.y, a);
      a = fmaf(zb.z, wb.z, a); a = fmaf(zb.w, wb.w, a);
      a = fmaf(zc.x, wc.x, a); a = fmaf(zc.y, wc.y, a);
      a = fmaf(zc.z, wc.z, a); a = fmaf(zc.w, wc.w, a);
      a = fmaf(zd.x, wd.x, a); a = fmaf(zd.y, wd.y, a);
      a = fmaf(zd.z, wd.z, a); a = fmaf(zd.w, wd.w, a);
      acc[b] = a;
    }
  }
  #pragma unroll
  for (int b = 0; b < 16; ++b) acc[b] = __expf(acc[b]);
  #pragma unroll
  for (int b = 0; b < 16; ++b) {
    float v = acc[b];
    #pragma unroll
    for (int o = 32; o >= 1; o >>= 1) v += __shfl_xor(v, o, 64);
    if (lane == 0) red[wid][b] = v;
  }
  __syncthreads();
  #pragma unroll
  for (int b = 0; b < 16; ++b) {
    const float s = red[0][b] + red[1][b] + red[2][b] + red[3][b];
    trans[(size_t)(bg * 16 + b) * (DA * DS * DS) + (size_t)ki * DS + j] =
        __float2half(acc[b] / s);
  }
}

// ---------------- M precompute: M[tt,b,i,j] = sum_k alpha_a[t0+tt,b,k] * T[b,k,i,j] ----------------
__global__ __launch_bounds__(256) void k_mbuild(const __half* __restrict__ trans,
                                                const float* __restrict__ alpha_a,
                                                __half* __restrict__ Mch,
                                                int t0, int TC) {
  const int b = blockIdx.x >> 4;
  const int ich = (blockIdx.x & 15) << 4;
  const int tid = threadIdx.x;
  const int lane = tid & 63;
  const int wid = tid >> 6;
  __shared__ float a_lds[32 * DA];  // TC <= 32
  for (int r = tid; r < TC * DA; r += 256)
    a_lds[r] = alpha_a[((size_t)(t0 + (r >> 4)) * DB + b) * DA + (r & 15)];
  __syncthreads();
  for (int io = 0; io < 4; ++io) {
    const int i = ich + io * 4 + wid;
    const __half* tp = trans + ((size_t)b * DA * DS + i) * DS + lane * 4;
    float Tf[64];
    #pragma unroll
    for (int k = 0; k < 16; ++k) {
      HV2 u;
      u.i2 = *reinterpret_cast<const int2*>(tp + (size_t)k * (DS * DS));
      const float2 f0 = __half22float2(u.h2[0]);
      const float2 f1 = __half22float2(u.h2[1]);
      Tf[k * 4 + 0] = f0.x; Tf[k * 4 + 1] = f0.y;
      Tf[k * 4 + 2] = f1.x; Tf[k * 4 + 3] = f1.y;
    }
    for (int tt = 0; tt < TC; ++tt) {
      float m0 = 0.f, m1 = 0.f, m2 = 0.f, m3 = 0.f;
      #pragma unroll
      for (int k = 0; k < 16; ++k) {
        const float ak = a_lds[tt * DA + k];
        m0 = fmaf(ak, Tf[k * 4 + 0], m0);
        m1 = fmaf(ak, Tf[k * 4 + 1], m1);
        m2 = fmaf(ak, Tf[k * 4 + 2], m2);
        m3 = fmaf(ak, Tf[k * 4 + 3], m3);
      }
      HV2 o;
      o.h2[0] = __floats2half2_rn(m0, m1);
      o.h2[1] = __floats2half2_rn(m2, m3);
      *reinterpret_cast<int2*>(Mch + (((size_t)tt * DB + b) * DS + i) * DS + lane * 4) = o.i2;
    }
  }
}

// ---------------- scan chunk v2: 1024 threads/b, cross-step dbuf, LDS-only barriers ----------------
// Per step: thread (jg = tid&31 -> 8 j's, iq = tid>>5 -> i = IT*32+iq, IT=0..7).
// Raw s_barrier + lgkmcnt(0) (NOT __syncthreads): prefetched global loads for step t+1
// stay in flight across the softmax barriers; compiler inserts vmcnt waits at their use.
#define LBAR() asm volatile("s_waitcnt lgkmcnt(0)\n\ts_barrier" ::: "memory")

#define SC_ISSUE(S, T)                                                          \
  if ((T) < TC) {                                                               \
    const __half* mb_ = Mch + (((size_t)(T) * DB + b) << 16) + jg * 8;          \
    S##0 = *reinterpret_cast<const int4*>(mb_ + (size_t)(iq + 0 * 32) * DS);    \
    S##1 = *reinterpret_cast<const int4*>(mb_ + (size_t)(iq + 1 * 32) * DS);    \
    S##2 = *reinterpret_cast<const int4*>(mb_ + (size_t)(iq + 2 * 32) * DS);    \
    S##3 = *reinterpret_cast<const int4*>(mb_ + (size_t)(iq + 3 * 32) * DS);    \
    S##4 = *reinterpret_cast<const int4*>(mb_ + (size_t)(iq + 4 * 32) * DS);    \
    S##5 = *reinterpret_cast<const int4*>(mb_ + (size_t)(iq + 5 * 32) * DS);    \
    S##6 = *reinterpret_cast<const int4*>(mb_ + (size_t)(iq + 6 * 32) * DS);    \
    S##7 = *reinterpret_cast<const int4*>(mb_ + (size_t)(iq + 7 * 32) * DS);    \
    if (tid < DS) lo_##S = logp_o[((size_t)(t0 + (T)) * DB + b) * DS + tid];    \
  }

#define SC_ACC1(Q, IT) {                                                 \
    const float wgt = bl[(IT) * 32 + iq];                                \
    HV u; u.i4 = (Q);                                                    \
    const float2 f0 = __half22float2(u.h2[0]);                           \
    const float2 f1 = __half22float2(u.h2[1]);                           \
    const float2 f2 = __half22float2(u.h2[2]);                           \
    const float2 f3 = __half22float2(u.h2[3]);                           \
    acc0 = fmaf(wgt, f0.x, acc0); acc1 = fmaf(wgt, f0.y, acc1);          \
    acc2 = fmaf(wgt, f1.x, acc2); acc3 = fmaf(wgt, f1.y, acc3);          \
    acc4 = fmaf(wgt, f2.x, acc4); acc5 = fmaf(wgt, f2.y, acc5);          \
    acc6 = fmaf(wgt, f3.x, acc6); acc7 = fmaf(wgt, f3.y, acc7); }

#define SC_STEP(S, T) {                                                  \
    float acc0=0.f,acc1=0.f,acc2=0.f,acc3=0.f,acc4=0.f,acc5=0.f,acc6=0.f,acc7=0.f; \
    SC_ACC1(S##0, 0) SC_ACC1(S##1, 1) SC_ACC1(S##2, 2) SC_ACC1(S##3, 3)  \
    SC_ACC1(S##4, 4) SC_ACC1(S##5, 5) SC_ACC1(S##6, 6) SC_ACC1(S##7, 7)  \
    acc0 += __shfl_xor(acc0, 32, 64); acc1 += __shfl_xor(acc1, 32, 64);  \
    acc2 += __shfl_xor(acc2, 32, 64); acc3 += __shfl_xor(acc3, 32, 64);  \
    acc4 += __shfl_xor(acc4, 32, 64); acc5 += __shfl_xor(acc5, 32, 64);  \
    acc6 += __shfl_xor(acc6, 32, 64); acc7 += __shfl_xor(acc7, 32, 64);  \
    if (lane < 32) {                                                     \
      red[w][lane][0] = acc0; red[w][lane][1] = acc1;                    \
      red[w][lane][2] = acc2; red[w][lane][3] = acc3;                    \
      red[w][lane][4] = acc4; red[w][lane][5] = acc5;                    \
      red[w][lane][6] = acc6; red[w][lane][7] = acc7;                    \
    }                                                                    \
    LBAR();                                                              \
    float e = 0.f, l = 0.f;                                              \
    if (tid < DS) {                                                      \
      const int jj = tid >> 3, qq = tid & 7;                             \
      float sv = 0.f;                                                    \
      sv += red[0][jj][qq];  sv += red[1][jj][qq];                       \
      sv += red[2][jj][qq];  sv += red[3][jj][qq];                       \
      sv += red[4][jj][qq];  sv += red[5][jj][qq];                       \
      sv += red[6][jj][qq];  sv += red[7][jj][qq];                       \
      sv += red[8][jj][qq];  sv += red[9][jj][qq];                       \
      sv += red[10][jj][qq]; sv += red[11][jj][qq];                      \
      sv += red[12][jj][qq]; sv += red[13][jj][qq];                      \
      sv += red[14][jj][qq]; sv += red[15][jj][qq];                      \
      l = __logf(sv + 1e-6f) + lo_##S;                                   \
      float m = l;                                                       \
      m = fmaxf(m, __shfl_xor(m, 32, 64)); m = fmaxf(m, __shfl_xor(m, 16, 64)); \
      m = fmaxf(m, __shfl_xor(m, 8, 64));  m = fmaxf(m, __shfl_xor(m, 4, 64));  \
      m = fmaxf(m, __shfl_xor(m, 2, 64));  m = fmaxf(m, __shfl_xor(m, 1, 64));  \
      if (lane == 0) redm[w] = m;                                        \
    }                                                                    \
    LBAR();                                                              \
    if (tid < DS) {                                                      \
      const float m = fmaxf(fmaxf(redm[0], redm[1]), fmaxf(redm[2], redm[3])); \
      e = __expf(l - m);                                                 \
      float v = e;                                                       \
      v += __shfl_xor(v, 32, 64); v += __shfl_xor(v, 16, 64);            \
      v += __shfl_xor(v, 8, 64);  v += __shfl_xor(v, 4, 64);             \
      v += __shfl_xor(v, 2, 64);  v += __shfl_xor(v, 1, 64);             \
      if (lane == 0) reds[w] = v;                                        \
    }                                                                    \
    LBAR();                                                              \
    if (tid < DS) {                                                      \
      const float p = e / (reds[0] + reds[1] + reds[2] + reds[3]);       \
      bl[tid] = p;                                                       \
      out_b[((size_t)(t0 + (T)) * DB + b) * DS + tid] = p;               \
    }                                                                    \
    LBAR(); }

__global__ __launch_bounds__(1024, 4) void k_scanchunk(
    const __half* __restrict__ Mch,
    const float* __restrict__ logp_o,
    const float* __restrict__ b0,
    float* __restrict__ bl_buf,
    float* __restrict__ out_b,
    int t0, int TC) {
  const int b = blockIdx.x;
  const int tid = threadIdx.x;
  const int lane = tid & 63;
  const int w = tid >> 6;        // wave 0..15
  const int jg = tid & 31;       // j-group of 8
  const int iq = tid >> 5;       // i phase 0..31
  __shared__ __align__(16) float bl[DS];
  __shared__ float red[16][32][9];   // +1 pad: conflict-free stores
  __shared__ float redm[4], reds[4];
  if (tid < DS) bl[tid] = (t0 == 0) ? b0[b * DS + tid] : bl_buf[b * DS + tid];
  __syncthreads();

  int4 A0, A1, A2, A3, A4, A5, A6, A7;
  int4 B0, B1, B2, B3, B4, B5, B6, B7;
  float lo_A = 0.f, lo_B = 0.f;

  SC_ISSUE(A, 0)
  for (int tt = 0; tt < TC; tt += 2) {   // TC is even
    SC_ISSUE(B, tt + 1)
    SC_STEP(A, tt)
    SC_ISSUE(A, tt + 2)
    SC_STEP(B, tt + 1)
  }
  if (tid < DS) bl_buf[b * DS + tid] = bl[tid];
}

// ---------------- plan mega-kernel: grid = T*B wgs ----------------
__global__ __launch_bounds__(256) void k_planall(const float* __restrict__ out_b,
                                                 const __half* __restrict__ value16,
                                                 const float* __restrict__ h_dist,
                                                 float* __restrict__ out_pi) {
  const int b = blockIdx.x & 63;
  const int t = blockIdx.x >> 6;
  const int tid = threadIdx.x;
  const int lane = tid & 63;
  const int wid = tid >> 6;
  __shared__ __align__(16) float bl[DS];
  __shared__ float api[DA];
  bl[tid] = out_b[((size_t)t * DB + b) * DS + tid];
  if (tid < DA) api[tid] = 0.f;
  __syncthreads();
  const int k = lane >> 2;
  const int q = lane & 3;
  for (int p = 0; p < 8; ++p) {
    const int h = p * 4 + wid;
    if (h < DH) {
      const __half* vr = value16 + (((size_t)h * DB + b) * DA + k) * DS + q * 64;
      const float* blq = bl + q * 64;
      float dot = 0.f;
      #pragma unroll
      for (int ii = 0; ii < 64; ii += 8) {
        HV u;
        u.i4 = *reinterpret_cast<const int4*>(vr + ii);
        const float4 c0 = *reinterpret_cast<const float4*>(blq + ii);
        const float4 c1 = *reinterpret_cast<const float4*>(blq + ii + 4);
        const float2 f0 = __half22float2(u.h2[0]);
        const float2 f1 = __half22float2(u.h2[1]);
        const float2 f2 = __half22float2(u.h2[2]);
        const float2 f3 = __half22float2(u.h2[3]);
        dot = fmaf(f0.x, c0.x, dot); dot = fmaf(f0.y, c0.y, dot);
        dot = fmaf(f1.x, c0.z, dot); dot = fmaf(f1.y, c0.w, dot);
        dot = fmaf(f2.x, c1.x, dot); dot = fmaf(f2.y, c1.y, dot);
        dot = fmaf(f3.x, c1.z, dot); dot = fmaf(f3.y, c1.w, dot);
      }
      dot += __shfl_xor(dot, 1, 64);
      dot += __shfl_xor(dot, 2, 64);
      float mk = dot;
      #pragma unroll
      for (int o = 4; o <= 32; o <<= 1) mk = fmaxf(mk, __shfl_xor(mk, o, 64));
      const float ek = __expf(dot - mk);
      float sk = ek;
      #pragma unroll
      for (int o = 4; o <= 32; o <<= 1) sk += __shfl_xor(sk, o, 64);
      if (q == 0) atomicAdd(&api[k], (ek / sk) * h_dist[b * DH + h]);
    }
  }
  __syncthreads();
  if (tid < DA) out_pi[((size_t)t * DB + b) * DA + tid] = api[tid];
}

// ---------------- fallback per-step kernel (R5) for small ws ----------------
#define K_LD(I) (*reinterpret_cast<const int4*>(tb + (size_t)((I) * 64 + rb) * DS))
#define K_FMA(QV, I) {                                              \
    HV u; u.i4 = (QV);                                              \
    const float wgt = wv[(I) * 64 + rb];                            \
    const float2 f0 = __half22float2(u.h2[0]);                      \
    const float2 f1 = __half22float2(u.h2[1]);                      \
    const float2 f2 = __half22float2(u.h2[2]);                      \
    const float2 f3 = __half22float2(u.h2[3]);                      \
    acc[0] = fmaf(wgt, f0.x, acc[0]); acc[1] = fmaf(wgt, f0.y, acc[1]); \
    acc[2] = fmaf(wgt, f1.x, acc[2]); acc[3] = fmaf(wgt, f1.y, acc[3]); \
    acc[4] = fmaf(wgt, f2.x, acc[4]); acc[5] = fmaf(wgt, f2.y, acc[5]); \
    acc[6] = fmaf(wgt, f3.x, acc[6]); acc[7] = fmaf(wgt, f3.y, acc[7]); }

__global__ __launch_bounds__(256, 2) void k_step(
    const __half* __restrict__ trans, const float* __restrict__ logp_o,
    const float* __restrict__ logp_u, const __half* __restrict__ value16,
    const float* __restrict__ h_dist, const float* __restrict__ b0,
    float* __restrict__ s_buf, float* __restrict__ out_b,
    float* __restrict__ out_pi, int t) {
  const int bb = blockIdx.x & 63;
  const int jt = blockIdx.x >> 6;
  const int tid = threadIdx.x;
  const int lane = tid & 63;
  const int wid = tid >> 6;
  __shared__ __align__(16) float wv[DA * DS];
  __shared__ __align__(16) float bl[DS];
  __shared__ float aa[DA];
  __shared__ float redm[4], reds[4];
  __shared__ float red4[4][4][8];
  __shared__ float api[DA];
  if (t > 0) {
    const int tp = t - 1;
    const float sv = s_buf[(size_t)(tp & 1) * DB * DS + bb * DS + tid];
    const float l = __logf(sv + 1e-6f) + logp_o[((size_t)tp * DB + bb) * DS + tid];
    float m = l;
    #pragma unroll
    for (int o = 32; o >= 1; o >>= 1) m = fmaxf(m, __shfl_xor(m, o, 64));
    if (lane == 0) redm[wid] = m;
    __syncthreads();
    m = fmaxf(fmaxf(redm[0], redm[1]), fmaxf(redm[2], redm[3]));
    const float e = __expf(l - m);
    float v = e;
    #pragma unroll
    for (int o = 32; o >= 1; o >>= 1) v += __shfl_xor(v, o, 64);
    if (lane == 0) reds[wid] = v;
    if (tid < DA) api[tid] = 0.f;
    __syncthreads();
    const float p = e / (reds[0] + reds[1] + reds[2] + reds[3]);
    bl[tid] = p;
    if (jt == 0) out_b[((size_t)tp * DB + bb) * DS + tid] = p;
    __syncthreads();
    const int h = jt * 4 + wid;
    const int k = lane >> 2;
    const int q = lane & 3;
    if (h < DH) {
      const __half* vr = value16 + (((size_t)h * DB + bb) * DA + k) * DS + q * 64;
      const float* blq = bl + q * 64;
      float dot = 0.f;
      #pragma unroll
      for (int ii = 0; ii < 64; ii += 8) {
        HV u;
        u.i4 = *reinterpret_cast<const int4*>(vr + ii);
        const float4 c0 = *reinterpret_cast<const float4*>(blq + ii);
        const float4 c1 = *reinterpret_cast<const float4*>(blq + ii + 4);
        const float2 f0 = __half22float2(u.h2[0]);
        const float2 f1 = __half22float2(u.h2[1]);
        const float2 f2 = __half22float2(u.h2[2]);
        const float2 f3 = __half22float2(u.h2[3]);
        dot = fmaf(f0.x, c0.x, dot); dot = fmaf(f0.y, c0.y, dot);
        dot = fmaf(f1.x, c0.z, dot); dot = fmaf(f1.y, c0.w, dot);
        dot = fmaf(f2.x, c1.x, dot); dot = fmaf(f2.y, c1.y, dot);
        dot = fmaf(f3.x, c1.z, dot); dot = fmaf(f3.y, c1.w, dot);
      }
      dot += __shfl_xor(dot, 1, 64);
      dot += __shfl_xor(dot, 2, 64);
      float mk = dot;
      #pragma unroll
      for (int o = 4; o <= 32; o <<= 1) mk = fmaxf(mk, __shfl_xor(mk, o, 64));
      const float ek = __expf(dot - mk);
      float sk = ek;
      #pragma unroll
      for (int o = 4; o <= 32; o <<= 1) sk += __shfl_xor(sk, o, 64);
      if (q == 0) atomicAdd(&api[k], (ek / sk) * h_dist[bb * DH + h]);
    }
    __syncthreads();
    if (tid < DA) atomicAdd(&out_pi[((size_t)tp * DB + bb) * DA + tid], api[tid]);
  } else {
    bl[tid] = b0[bb * DS + tid];
  }
  __syncthreads();
  if (t < DT) {
    if (tid < DA) {
      const float lg = logp_u[((size_t)t * DB + bb) * DA + tid];
      float m = lg;
      #pragma unroll
      for (int o = 8; o >= 1; o >>= 1) m = fmaxf(m, __shfl_xor(m, o, 16));
      const float e = __expf(lg - m);
      float s = e;
      #pragma unroll
      for (int o = 8; o >= 1; o >>= 1) s += __shfl_xor(s, o, 16);
      aa[tid] = e / s;
    }
    __syncthreads();
    #pragma unroll
    for (int r = tid; r < DA * DS; r += 256) wv[r] = aa[r >> 8] * bl[r & 255];
    __syncthreads();
    const int jg = tid & 3;
    const int rb = tid >> 2;
    const __half* tb = trans + (size_t)bb * (DA * DS * DS) + jt * 32 + jg * 8;
    float acc[8] = {0.f, 0.f, 0.f, 0.f, 0.f, 0.f, 0.f, 0.f};
    int4 Q0 = K_LD(0), Q1 = K_LD(1), Q2 = K_LD(2), Q3 = K_LD(3);
    int4 Q4 = K_LD(4), Q5 = K_LD(5), Q6 = K_LD(6), Q7 = K_LD(7);
    #pragma unroll
    for (int it = 0; it < 56; it += 8) {
      K_FMA(Q0, it + 0); Q0 = K_LD(it + 8);
      K_FMA(Q1, it + 1); Q1 = K_LD(it + 9);
      K_FMA(Q2, it + 2); Q2 = K_LD(it + 10);
      K_FMA(Q3, it + 3); Q3 = K_LD(it + 11);
      K_FMA(Q4, it + 4); Q4 = K_LD(it + 12);
      K_FMA(Q5, it + 5); Q5 = K_LD(it + 13);
      K_FMA(Q6, it + 6); Q6 = K_LD(it + 14);
      K_FMA(Q7, it + 7); Q7 = K_LD(it + 15);
    }
    K_FMA(Q0, 56); K_FMA(Q1, 57); K_FMA(Q2, 58); K_FMA(Q3, 59);
    K_FMA(Q4, 60); K_FMA(Q5, 61); K_FMA(Q6, 62); K_FMA(Q7, 63);
    #pragma unroll
    for (int q = 0; q < 8; ++q) {
      acc[q] += __shfl_xor(acc[q], 4, 64);
      acc[q] += __shfl_xor(acc[q], 8, 64);
      acc[q] += __shfl_xor(acc[q], 16, 64);
      acc[q] += __shfl_xor(acc[q], 32, 64);
    }
    if (lane < 4) {
      #pragma unroll
      for (int q = 0; q < 8; ++q) red4[wid][lane][q] = acc[q];
    }
    __syncthreads();
    if (tid < 32) {
      const int jg2 = tid >> 3, q2 = tid & 7;
      const float s = red4[0][jg2][q2] + red4[1][jg2][q2] +
                      red4[2][jg2][q2] + red4[3][jg2][q2];
      s_buf[(size_t)(t & 1) * DB * DS + bb * DS + jt * 32 + jg2 * 8 + q2] = s;
    }
  }
}

// ---------------- launch ----------------

extern "C" void kernel_launch(void* const* d_in, const int* in_sizes, int n_in,
                              void* d_out, int out_size, void* d_ws, size_t ws_size,
                              hipStream_t stream) {
  const float* logp_o = (const float*)d_in[0];
  const float* logp_u = (const float*)d_in[1];
  const float* value  = (const float*)d_in[2];
  const float* z      = (const float*)d_in[3];
  const float* b0     = (const float*)d_in[4];
  const float* w      = (const float*)d_in[5];
  const float* wofs   = (const float*)d_in[6];
  const float* tau    = (const float*)d_in[7];
  const float* tauw   = (const float*)d_in[8];

  char* ws = (char*)d_ws;
  size_t off = 0;
  __half* trans   = (__half*)(ws + off); off += (size_t)DB * DA * DS * DS * sizeof(__half);
  __half* value16 = (__half*)(ws + off); off += (size_t)DH * DB * DA * DS * sizeof(__half);
  float* alpha_a  = (float*)(ws + off);  off += (size_t)DT * DB * DA * sizeof(float);
  float* s_buf    = (float*)(ws + off);  off += (size_t)2 * DB * DS * sizeof(float);
  float* bl_buf   = (float*)(ws + off);  off += (size_t)DB * DS * sizeof(float);
  float* h_dist   = (float*)(ws + off);  off += 8192;
  const size_t base = off;
  if (base > ws_size) return;
  __half* M = (__half*)(ws + base);
  const size_t m_per_t = (size_t)DB * DS * DS * sizeof(__half);  // 8,388,608 B
  int TC = 0;
  const int cands[5] = {32, 16, 8, 4, 2};   // even only (A/B pipeline)
  for (int c = 0; c < 5; ++c)
    if (base + (size_t)cands[c] * m_per_t <= ws_size) { TC = cands[c]; break; }

  float* out_b  = (float*)d_out;
  float* out_pi = out_b + (size_t)DT * DB * DS;

  k_hdist<<<1, 64, 0, stream>>>(z, tau, tauw, h_dist);
  k_vconv<<<1024, 256, 0, stream>>>(value, value16, DH * DB * DA * DS / 4);
  k_trans<<<DA * DS * 4, 256, 0, stream>>>(w, wofs, z, trans);

  if (TC) {
    k_alpha<<<256, 256, 0, stream>>>(logp_u, alpha_a);
    for (int c = 0; c < DT / TC; ++c) {
      k_mbuild<<<DB * 16, 256, 0, stream>>>(trans, alpha_a, M, c * TC, TC);
      k_scanchunk<<<DB, 1024, 0, stream>>>(M, logp_o, b0, bl_buf, out_b, c * TC, TC);
    }
    k_planall<<<DT * DB, 256, 0, stream>>>(out_b, value16, h_dist, out_pi);
  } else {
    k_zero<<<256, 256, 0, stream>>>(out_pi);
    for (int t = 0; t <= DT; ++t) {
      k_step<<<512, 256, 0, stream>>>(trans, logp_o, logp_u, value16, h_dist, b0,
                                      s_buf, out_b, out_pi, t);
    }
  }
}